// Round 4
// baseline (87.727 us; speedup 1.0000x reference)
//
#include <hip/hip_runtime.h>
#include <hip/hip_bf16.h>

// Problem constants (setup_inputs: B=64, S=1024, H=128, A=8, CTX_WIN=5, PAD=2)
#define S_DIM 1024
#define H_DIM 128
#define A_DIM 8
#define W_WIN 5

typedef unsigned int uint;
typedef unsigned short ushort;
typedef __attribute__((ext_vector_type(8))) short short8;   // 8 bf16 = 4 VGPRs
typedef __attribute__((ext_vector_type(4))) float f32x4;

union U128 { uint4 u; short8 s; };

__device__ __forceinline__ ushort f2bf(float f) {
    uint u = __float_as_uint(f);
    uint r = (u + 0x7fffu + ((u >> 16) & 1u)) >> 16;   // round-to-nearest-even
    return (ushort)r;
}

// ---------------------------------------------------------------------------
// K1: grid (8 h-chunks, 8 aspects) x 128 threads.
//   Gt[a][w*128+h] = sum_f P[a,h,f] * E[a,f,w], bf16. 4-deep load chain.
// ---------------------------------------------------------------------------
__global__ __launch_bounds__(128) void k_g(const float* __restrict__ P,
                                           const float* __restrict__ We,
                                           ushort* __restrict__ Gt) {
    const int a  = blockIdx.y;       // 0..7
    const int hc = blockIdx.x;       // 0..7 (16-row chunk)
    const int t  = threadIdx.x;

    __shared__ float Es[H_DIM * W_WIN];             // 2560 B: E[a] (f-major, w inner)
    __shared__ float red[16 * 8 * W_WIN];           // 2560 B: partials [hl][fo][w]
    for (int i = t; i < H_DIM * W_WIN; i += 128) Es[i] = We[a * (H_DIM * W_WIN) + i];
    __syncthreads();

    const int hl = t >> 3, fo = t & 7;
    const float* Pr = P + ((size_t)(a * H_DIM + hc * 16 + hl)) * H_DIM + fo * 16;
    float acc[W_WIN] = {0.f, 0.f, 0.f, 0.f, 0.f};
#pragma unroll
    for (int j4 = 0; j4 < 4; ++j4) {
        float4 pv = ((const float4*)Pr)[j4];
        float pj[4] = {pv.x, pv.y, pv.z, pv.w};
#pragma unroll
        for (int j = 0; j < 4; ++j) {
            const float* e = &Es[(fo * 16 + j4 * 4 + j) * W_WIN];
#pragma unroll
            for (int w = 0; w < W_WIN; ++w) acc[w] += pj[j] * e[w];
        }
    }
#pragma unroll
    for (int w = 0; w < W_WIN; ++w) red[(hl * 8 + fo) * W_WIN + w] = acc[w];
    __syncthreads();

    if (t < 80) {                     // 16 rows x 5 windows
        const int w = t >> 4, h2 = t & 15;
        float s = 0.f;
#pragma unroll
        for (int f8 = 0; f8 < 8; ++f8) s += red[(h2 * 8 + f8) * W_WIN + w];
        Gt[a * (W_WIN * H_DIM) + w * H_DIM + hc * 16 + h2] = f2bf(s);
    }
}

// ---------------------------------------------------------------------------
// K2: CS=128, 512 threads (8 waves), 512 blocks, LDS 48.8 KB.
// escore now written cooperatively from el after the phase-C barrier
// (full 64B lines, vs per-lane 32B half-line chunks in the hot phase).
// ---------------------------------------------------------------------------
#define CS 128
#define RROWS (CS + 4)        // 132
#define EPITCH 136            // el pitch bf16 (272 B: 16B-aligned)
__global__ __launch_bounds__(512) void k_scores(const float* __restrict__ Din,
                                                const ushort* __restrict__ Gt,
                                                ushort* __restrict__ escore,
                                                float* __restrict__ numPart,
                                                float* __restrict__ Zpart) {
    __shared__ uint4 Dl[RROWS * 16];      // 33792 B bf16 doc tile, XOR swizzle
    __shared__ uint4 Gl[9 * 80];          // 11520 B: 8 aspect rows + zero row
    __shared__ ushort el[16 * EPITCH];    // 4352 B  e as bf16, [a][s]
    __shared__ float Zw[64];              // 8 waves x 8 aspects
    const int b   = blockIdx.y;
    const int slc = blockIdx.x;           // 0..7
    const int s0  = slc * CS;
    const int t   = threadIdx.x;
    const float* Db = Din + (size_t)b * S_DIM * H_DIM;

    // --- stage doc rows [s0-2, s0+CS+2): issue-all-loads-first for ILP ---
    {
        const int c  = t & 15;
        const int r0 = t >> 4;            // 0..31
        float4 va[5], vb[5];
        bool ok[5];
#pragma unroll
        for (int k = 0; k < 4; ++k) {
            const int gs = s0 - 2 + r0 + k * 32;
            ok[k] = (gs >= 0) && (gs < S_DIM);
            const int gc = min(max(gs, 0), S_DIM - 1);
            const float4* p = (const float4*)(Db + (size_t)gc * H_DIM + c * 8);
            va[k] = p[0];
            vb[k] = p[1];
        }
        if (t < 64) {                              // tail rows 128..131
            const int gs = s0 - 2 + 128 + r0;
            ok[4] = (gs >= 0) && (gs < S_DIM);
            const int gc = min(max(gs, 0), S_DIM - 1);
            const float4* p = (const float4*)(Db + (size_t)gc * H_DIM + c * 8);
            va[4] = p[0];
            vb[4] = p[1];
        }
#pragma unroll
        for (int k = 0; k < 5; ++k) {
            if (k == 4 && t >= 64) break;
            const int r = (k == 4) ? (128 + r0) : (r0 + k * 32);
            float4 A = va[k], Bv = vb[k];
            if (!ok[k]) { A = make_float4(0.f,0.f,0.f,0.f); Bv = A; }
            uint4 q;
            q.x = (uint)f2bf(A.x)  | ((uint)f2bf(A.y)  << 16);
            q.y = (uint)f2bf(A.z)  | ((uint)f2bf(A.w)  << 16);
            q.z = (uint)f2bf(Bv.x) | ((uint)f2bf(Bv.y) << 16);
            q.w = (uint)f2bf(Bv.z) | ((uint)f2bf(Bv.w) << 16);
            Dl[r * 16 + (c ^ (r & 15))] = q;
        }
    }
    // --- stage Gl: rows 0..7 = Gt aspects, row 8 = zeros; chunk XOR swizzle ---
    {
        const uint4* Gg = (const uint4*)Gt;
        for (int i = t; i < 9 * 80; i += 512) {
            const int n = i / 80, c = i - n * 80;
            uint4 v = make_uint4(0u, 0u, 0u, 0u);
            if (n < 8) v = Gg[n * 80 + c];
            Gl[n * 80 + ((c & ~15) | ((c & 15) ^ n))] = v;
        }
    }
    __syncthreads();

    const int lane = t & 63;
    const int wv   = t >> 6;          // wave id 0..7 -> m-tile (16 s-rows)
    const int lm   = lane & 15;
    const int lq   = lane >> 4;
    const int gr   = (lm < 8) ? lm : 8;   // Gl row (8 = shared zero row)

    // ---- Phase B: score MFMA (LDS-only inner loop) ----
    f32x4 acc0 = {0.f, 0.f, 0.f, 0.f};
#pragma unroll
    for (int kk = 0; kk < 20; ++kk) {
        const int w = kk >> 2;
        const int r0 = wv * 16 + lm + w;          // <= 131
        const int cidx = (kk & 3) * 4 + lq;
        const int gc = kk * 4 + lq;
        U128 av, bv;
        bv.u = Gl[gr * 80 + ((gc & ~15) | ((gc & 15) ^ gr))];
        av.u = Dl[r0 * 16 + (cidx ^ (r0 & 15))];
        acc0 = __builtin_amdgcn_mfma_f32_16x16x32_bf16(av.s, bv.s, acc0, 0, 0, 0);
    }

    // ---- Phase C: e = exp(score); el LDS, Z wave-partials ----
    // C layout: col(a)=lm, rows s = wv*16 + lq*4 + r
    float4 e0;
    e0.x = __expf(acc0.x); e0.y = __expf(acc0.y); e0.z = __expf(acc0.z); e0.w = __expf(acc0.w);
    uint2 d0;
    d0.x = (uint)f2bf(e0.x) | ((uint)f2bf(e0.y) << 16);
    d0.y = (uint)f2bf(e0.z) | ((uint)f2bf(e0.w) << 16);
    const int sb = wv * 16 + lq * 4;              // 0..124
    *(uint2*)(&el[lm * EPITCH + sb]) = d0;   // rows a>=8 hold exp(0)=1: unused

    float es = e0.x + e0.y + e0.z + e0.w;
    es += __shfl_xor(es, 16);
    es += __shfl_xor(es, 32);
    if (lq == 0 && lm < A_DIM) Zw[wv * 8 + lm] = es;
    __syncthreads();

    // ---- cooperative escore store: 8 aspect rows x 256B, full 64B lines ----
    if (t < 128) {
        const int row = t >> 4, ci = t & 15;      // 16B chunk per thread
        const uint4 q = *(const uint4*)(&el[row * EPITCH + ci * 8]);
        *(uint4*)(escore + (((size_t)b * A_DIM + row) << 10) + s0 + ci * 8) = q;
    }

    // ---- Phase D: numerator MFMA  C[m=a][n=h], K=s=128 (4-chain) ----
    const ushort* Dls = (const ushort*)Dl;
    U128 afr[4];
#pragma unroll
    for (int kk = 0; kk < 4; ++kk)
        afr[kk].u = *(const uint4*)(&el[lm * EPITCH + kk * 32 + lq * 8]);

    f32x4 accN = {0.f, 0.f, 0.f, 0.f};
    {
        const int h  = wv * 16 + lm;              // 0..127
        const int ch = h >> 3, hw = h & 7;
#pragma unroll
        for (int kk = 0; kk < 4; ++kk) {
            uint p[4];
#pragma unroll
            for (int jj = 0; jj < 4; ++jj) {
                const int sj = kk * 32 + lq * 8 + jj * 2;
                const int ra = sj + 2, rb = sj + 3;   // +2 halo offset, <=129
                const uint lo = Dls[(ra * 16 + (ch ^ (ra & 15))) * 8 + hw];
                const uint hi = Dls[(rb * 16 + (ch ^ (rb & 15))) * 8 + hw];
                p[jj] = lo | (hi << 16);
            }
            U128 bfr; bfr.u = make_uint4(p[0], p[1], p[2], p[3]);
            accN = __builtin_amdgcn_mfma_f32_16x16x32_bf16(afr[kk].s, bfr.s, accN, 0, 0, 0);
        }
    }

    // ---- Phase E: per-slice partials, pure stores (8 slices per b) ----
    if (lq < 2) {   // C rows m = lq*4+r = aspect 0..7
        const int h = wv * 16 + lm;
#pragma unroll
        for (int r = 0; r < 4; ++r)
            numPart[(((size_t)(b * 8 + slc) * 8) + lq * 4 + r) * H_DIM + h] = accN[r];
    }
    if (t < A_DIM) {
        float z = 0.f;
#pragma unroll
        for (int k = 0; k < 8; ++k) z += Zw[k * 8 + t];
        Zpart[(b * 8 + slc) * 8 + t] = z;
    }
}

// ---------------------------------------------------------------------------
// K3: per (b,a), 256 threads. attn normalize in one coalesced shot (4 elems
// per thread); rep GEMV split-K across thread halves (64-deep chain, LDS
// combine). Critical path ~halved vs 128-thread version.
// ---------------------------------------------------------------------------
__global__ __launch_bounds__(256) void k_final(const ushort* __restrict__ escore,
                                               const float* __restrict__ numPart,
                                               const float* __restrict__ Zpart,
                                               const float* __restrict__ P,
                                               float* __restrict__ attn,
                                               float* __restrict__ rep) {
    __shared__ float ws[H_DIM];
    __shared__ float par[256];
    const int ba = blockIdx.x;                // b*8 + a
    const int b = ba >> 3, a = ba & 7;
    const int t = threadIdx.x;

    float Zs = 0.f;
#pragma unroll
    for (int k = 0; k < 8; ++k) Zs += Zpart[(b * 8 + k) * 8 + a];
    const float rz = 1.0f / Zs;

    if (t < H_DIM) {
        float s = 0.f;
#pragma unroll
        for (int k = 0; k < 8; ++k)
            s += numPart[(((size_t)(b * 8 + k) * 8) + a) * H_DIM + t];
        ws[t] = s * rz;
    }

    // attn: 1024 elems / 256 threads = 4 per thread, fully coalesced
    {
        const ushort* ep = escore + (size_t)ba * S_DIM;
        float* ap = attn + (size_t)ba * S_DIM;
        uint2 q = *(const uint2*)(ep + t * 4);
        float4 v;
        v.x = __uint_as_float(q.x << 16) * rz;
        v.y = __uint_as_float(q.x & 0xffff0000u) * rz;
        v.z = __uint_as_float(q.y << 16) * rz;
        v.w = __uint_as_float(q.y & 0xffff0000u) * rz;
        *(float4*)(ap + t * 4) = v;
    }
    __syncthreads();

    // rep GEMV: f = t&127, K-half kh = t>>7 over h in [kh*64, kh*64+64)
    const int f  = t & 127, kh = t >> 7;
    const float* Pa = P + (size_t)a * H_DIM * H_DIM + f;
    float acc = 0.f;
#pragma unroll 16
    for (int hh = 0; hh < 64; ++hh) {
        const int h = kh * 64 + hh;
        acc += ws[h] * Pa[(size_t)h * H_DIM];
    }
    par[t] = acc;
    __syncthreads();
    if (t < 128)
        rep[(size_t)ba * H_DIM + t] = par[t] + par[t + 128];
}

// ---------------------------------------------------------------------------
extern "C" void kernel_launch(void* const* d_in, const int* in_sizes, int n_in,
                              void* d_out, int out_size, void* d_ws, size_t ws_size,
                              hipStream_t stream) {
    const float* docIn = (const float*)d_in[0];   // (B, S, H) fp32
    const float* We    = (const float*)d_in[1];   // (A, 5*H)  fp32
    const float* P     = (const float*)d_in[2];   // (A, H, H) fp32
    float* out = (float*)d_out;                   // [B*A*S attn | B*A*H rep]

    const int B = in_sizes[0] / (S_DIM * H_DIM);  // 64

    ushort* Gt     = (ushort*)d_ws;                                   // 10 KB
    ushort* escore = (ushort*)((char*)d_ws + 32768);                  // B*A*S bf16 = 1 MB
    float* numPart = (float*)((char*)d_ws + 32768 +
                              (size_t)B * A_DIM * S_DIM * 2);         // B*8*8*H = 2 MB
    float* Zpart   = numPart + (size_t)B * 8 * 8 * H_DIM;             // B*8*8

    k_g<<<dim3(8, 8), 128, 0, stream>>>(P, We, Gt);
    k_scores<<<dim3(S_DIM / CS, B), 512, 0, stream>>>(docIn, Gt, escore, numPart, Zpart);
    k_final<<<B * A_DIM, 256, 0, stream>>>(escore, numPart, Zpart, P, out,
                                           out + (size_t)B * A_DIM * S_DIM);
}